// Round 5
// baseline (296.309 us; speedup 1.0000x reference)
//
#include <hip/hip_runtime.h>
#include <hip/hip_bf16.h>

typedef __attribute__((ext_vector_type(8))) short short8;
typedef __attribute__((ext_vector_type(4))) float f32x4;

static inline int cdiv(int a, int b) { return (a + b - 1) / b; }

__device__ inline float bf2f(unsigned short u) {
    union { unsigned int u; float f; } a; a.u = ((unsigned int)u) << 16; return a.f;
}
__device__ inline unsigned short f2bf(float f) {
    union { float f; unsigned int u; } a; a.f = f;
    unsigned int r = a.u + 0x7fff + ((a.u >> 16) & 1);
    return (unsigned short)(r >> 16);
}
__device__ inline void gload_lds16(const void* g, void* l) {
    __builtin_amdgcn_global_load_lds(
        (const __attribute__((address_space(1))) unsigned int*)g,
        (__attribute__((address_space(3))) unsigned int*)l, 16, 0, 0);
}

// ---------------- preprocessing ----------------
// deg (float, by source) and indeg (int, by target) in one edge pass
__global__ __launch_bounds__(256) void count_both_k(
    const int* __restrict__ rows, const int* __restrict__ cols,
    float* deg, int* indeg, int E)
{
    int e = blockIdx.x * 256 + threadIdx.x;
    if (e < E) {
        atomicAdd(&deg[rows[e]], 1.0f);
        atomicAdd(&indeg[cols[e]], 1);
    }
}

__global__ __launch_bounds__(256) void scan_block_k(
    const int* __restrict__ indeg, int* __restrict__ rowstart, int* __restrict__ bsums, int N)
{
    __shared__ int smem[256];
    int b = blockIdx.x, t = threadIdx.x;
    int base = b * 1024 + t * 4;
    int v0 = (base + 0 < N) ? indeg[base + 0] : 0;
    int v1 = (base + 1 < N) ? indeg[base + 1] : 0;
    int v2 = (base + 2 < N) ? indeg[base + 2] : 0;
    int v3 = (base + 3 < N) ? indeg[base + 3] : 0;
    int s = v0 + v1 + v2 + v3;
    smem[t] = s;
    __syncthreads();
    for (int off = 1; off < 256; off <<= 1) {
        int x = smem[t];
        int y = (t >= off) ? smem[t - off] : 0;
        __syncthreads();
        smem[t] = x + y;
        __syncthreads();
    }
    int excl = smem[t] - s;
    if (base + 0 < N) rowstart[base + 0] = excl;
    if (base + 1 < N) rowstart[base + 1] = excl + v0;
    if (base + 2 < N) rowstart[base + 2] = excl + v0 + v1;
    if (base + 3 < N) rowstart[base + 3] = excl + v0 + v1 + v2;
    if (t == 255) bsums[b] = smem[255];
}

__global__ __launch_bounds__(256) void scan_sums_k(int* bsums, int nb, int* rowstart, int N, int E) {
    __shared__ int smem[256];
    int t = threadIdx.x;
    int v = (t < nb) ? bsums[t] : 0;
    smem[t] = v;
    __syncthreads();
    for (int off = 1; off < 256; off <<= 1) {
        int x = smem[t];
        int y = (t >= off) ? smem[t - off] : 0;
        __syncthreads();
        smem[t] = x + y;
        __syncthreads();
    }
    if (t < nb) bsums[t] = smem[t] - v;
    if (t == 0) rowstart[N] = E;
}

// add block offsets, init cursor, and finish dinv = rsqrt(outdeg + 1[self])
__global__ __launch_bounds__(256) void scan_add_dinv_k(
    int* rowstart, int* cursor, const int* __restrict__ bsums, float* deg, int N)
{
    int i = blockIdx.x * 256 + threadIdx.x;
    if (i < N) {
        int v = rowstart[i] + bsums[i >> 10];
        rowstart[i] = v;
        cursor[i] = v;
        deg[i] = rsqrtf(deg[i] + 1.0f);
    }
}

__global__ __launch_bounds__(256) void fill_csr_k(
    const int* __restrict__ rows, const int* __restrict__ cols,
    int* cursor, int* __restrict__ csr, int E)
{
    int e = blockIdx.x * 256 + threadIdx.x;
    if (e < E) {
        int pos = atomicAdd(&cursor[cols[e]], 1);
        csr[pos] = rows[e];
    }
}

// ---------------- dtype conversion ----------------
__global__ __launch_bounds__(256) void f2b_k(const float* __restrict__ in, unsigned short* __restrict__ out, int n4) {
    int i = blockIdx.x * 256 + threadIdx.x;
    if (i >= n4) return;
    float4 v = ((const float4*)in)[i];
    ushort4 o;
    o.x = f2bf(v.x); o.y = f2bf(v.y); o.z = f2bf(v.z); o.w = f2bf(v.w);
    ((ushort4*)out)[i] = o;
}

// all three weight transposes (K x M -> Wt[m][k] bf16) in one launch
__global__ __launch_bounds__(256) void prep_weights_k(
    const float* __restrict__ W1, const float* __restrict__ W2, const float* __restrict__ Wh,
    unsigned short* __restrict__ Wt1, unsigned short* __restrict__ Wt2, unsigned short* __restrict__ Wht)
{
    int idx = blockIdx.x * 256 + threadIdx.x;
    if (idx < 65536) {
        int k = idx >> 8, m = idx & 255;
        Wt1[m * 256 + k] = f2bf(W1[idx]);
    } else if (idx < 131072) {
        int i = idx - 65536;
        int k = i >> 8, m = i & 255;
        Wt2[m * 256 + k] = f2bf(W2[i]);
    } else if (idx < 147456) {
        int i = idx - 131072;
        int k = i >> 6, m = i & 63;    // Wh is 256 x 64
        Wht[m * 256 + k] = f2bf(Wh[i]);
    }
}

// ---------------- MFMA GEMM, 2-phase double-buffered ----------------
// C[N,Ncols] = A[N,K](bf16) @ Wt[Ncols,K]^T(bf16) + bias
// MODE 0: out bf16, * rowscale[row]; MODE 1: out fp32 plain
// BM=128, BN in {64,128}, BK=64, 4 waves (2x2)
template<int BN, int MODE>
__global__ __launch_bounds__(256) void gemm_mfma_k(
    const unsigned short* __restrict__ A, const unsigned short* __restrict__ Wt,
    const float* __restrict__ bias, const float* __restrict__ rowscale,
    void* __restrict__ Cout, int N, int K, int Ncols)
{
    constexpr int NF = BN / 32;
    __shared__ __align__(16) unsigned short As[2][128 * 64];
    __shared__ __align__(16) unsigned short Bs[2][BN * 64];

    const int tid = threadIdx.x;
    const int wid = tid >> 6;
    const int lane = tid & 63;
    const int wr = wid >> 1;
    const int wc = wid & 1;
    const int rowBase = blockIdx.x * 128;
    const int colBase = blockIdx.y * BN;

    f32x4 acc[4][NF];
    #pragma unroll
    for (int m = 0; m < 4; ++m)
        #pragma unroll
        for (int n = 0; n < NF; ++n)
            acc[m][n] = (f32x4)0.0f;

    const int sslot = (lane & 7) ^ (lane >> 3);   // pre-swizzled source slot (m173)

    auto stage = [&](int buf, int k0) {
        #pragma unroll
        for (int it = 0; it < 4; ++it) {
            int ch = wid * 4 + it;
            int r = ch * 8 + (lane >> 3);
            int grow = rowBase + r; if (grow >= N) grow = N - 1;
            gload_lds16(A + (size_t)grow * K + k0 + sslot * 8, (void*)&As[buf][ch * 512]);
        }
        #pragma unroll
        for (int it = 0; it < NF; ++it) {
            int ch = wid * NF + it;
            int c = ch * 8 + (lane >> 3);
            gload_lds16(Wt + (size_t)(colBase + c) * K + k0 + sslot * 8, (void*)&Bs[buf][ch * 512]);
        }
    };

    const int nt = K >> 6;       // 4 for K=256
    stage(0, 0);
    __syncthreads();             // compiler drains vmcnt before barrier -> buf0 ready

    int cur = 0;
    for (int t = 0; t < nt; ++t) {
        if (t + 1 < nt) stage(cur ^ 1, (t + 1) * 64);   // prefetch next tile
        #pragma unroll
        for (int ks = 0; ks < 2; ++ks) {
            short8 af[4];
            #pragma unroll
            for (int m = 0; m < 4; ++m) {
                int R = wr * 64 + m * 16 + (lane & 15);
                int p = (ks * 4 + (lane >> 4)) ^ (R & 7);
                af[m] = *(const short8*)(&As[cur][R * 64 + p * 8]);
            }
            #pragma unroll
            for (int n = 0; n < NF; ++n) {
                int Cc = wc * (BN / 2) + n * 16 + (lane & 15);
                int p = (ks * 4 + (lane >> 4)) ^ (Cc & 7);
                short8 bf = *(const short8*)(&Bs[cur][Cc * 64 + p * 8]);
                #pragma unroll
                for (int m = 0; m < 4; ++m)
                    acc[m][n] = __builtin_amdgcn_mfma_f32_16x16x32_bf16(af[m], bf, acc[m][n], 0, 0, 0);
            }
        }
        if (t + 1 < nt) __syncthreads();   // next buf staged + this buf's reads done
        cur ^= 1;
    }

    // epilogue: C/D layout col=lane&15, row=(lane>>4)*4+q  [m89-verified]
    float bv[NF];
    int colv[NF];
    #pragma unroll
    for (int n = 0; n < NF; ++n) {
        colv[n] = colBase + wc * (BN / 2) + n * 16 + (lane & 15);
        bv[n] = bias[colv[n]];
    }
    #pragma unroll
    for (int m = 0; m < 4; ++m) {
        #pragma unroll
        for (int q = 0; q < 4; ++q) {
            int row = rowBase + wr * 64 + m * 16 + (lane >> 4) * 4 + q;
            if (row >= N) continue;
            if (MODE == 0) {
                float sc = rowscale[row];
                unsigned short* Cb = (unsigned short*)Cout;
                #pragma unroll
                for (int n = 0; n < NF; ++n)
                    Cb[(size_t)row * Ncols + colv[n]] = f2bf((acc[m][n][q] + bv[n]) * sc);
            } else {
                float* Cf = (float*)Cout;
                #pragma unroll
                for (int n = 0; n < NF; ++n)
                    Cf[(size_t)row * Ncols + colv[n]] = acc[m][n][q] + bv[n];
            }
        }
    }
}

// ---------------- XCD-sliced gather aggregate ----------------
// slice s = blockIdx.x & 7 handles features [s*32, s*32+32) -> per-XCD
// working set 50000*64B = 3.2MB < 4MB L2 (block->XCD round-robin heuristic).
// 16 threads per node (ushort2 each), 16 nodes per block.
__global__ __launch_bounds__(256) void gather_slice_k(
    const int* __restrict__ rowstart, const int* __restrict__ csr,
    const float* __restrict__ dinv, const unsigned short* __restrict__ hp,
    unsigned short* __restrict__ out, int N)
{
    int s = blockIdx.x & 7;
    int g = blockIdx.x >> 3;
    int t = threadIdx.x;
    int node = g * 16 + (t >> 4);
    if (node >= N) return;
    int col2 = s * 16 + (t & 15);          // ushort2 index within 128-wide row
    const ushort2* hp2 = (const ushort2*)hp;
    ushort2 sv = hp2[(size_t)node * 128 + col2];   // self loop
    float a0 = bf2f(sv.x), a1 = bf2f(sv.y);
    int beg = rowstart[node], end = rowstart[node + 1];
    int e = beg;
    for (; e + 1 < end; e += 2) {
        int r0 = csr[e], r1 = csr[e + 1];
        ushort2 v0 = hp2[(size_t)r0 * 128 + col2];
        ushort2 v1 = hp2[(size_t)r1 * 128 + col2];
        a0 += bf2f(v0.x) + bf2f(v1.x);
        a1 += bf2f(v0.y) + bf2f(v1.y);
    }
    if (e < end) {
        int r0 = csr[e];
        ushort2 v0 = hp2[(size_t)r0 * 128 + col2];
        a0 += bf2f(v0.x);
        a1 += bf2f(v0.y);
    }
    float sc = dinv[node];
    ushort2 o;
    o.x = f2bf(fmaxf(sc * a0, 0.f));
    o.y = f2bf(fmaxf(sc * a1, 0.f));
    ((ushort2*)out)[(size_t)node * 128 + col2] = o;
}

extern "C" void kernel_launch(void* const* d_in, const int* in_sizes, int n_in,
                              void* d_out, int out_size, void* d_ws, size_t ws_size,
                              hipStream_t stream) {
    const float* x  = (const float*)d_in[0];
    const int*  ei  = (const int*)d_in[1];
    const float* W1 = (const float*)d_in[2];
    const float* b1 = (const float*)d_in[3];
    const float* W2 = (const float*)d_in[4];
    const float* b2 = (const float*)d_in[5];
    const float* Wh = (const float*)d_in[6];
    const float* bh = (const float*)d_in[7];
    float* out = (float*)d_out;

    const int N = in_sizes[0] / 256;       // 50000
    const int E = in_sizes[1] / 2;         // 400000
    const int H = 256;
    const int C = 64;
    const int* rows = ei;
    const int* cols = ei + E;

    char* ws = (char*)d_ws;
    size_t off = 0;
    auto alloc = [&](size_t bytes) {
        void* p = ws + off;
        off = (off + bytes + 255) & ~(size_t)255;
        return p;
    };
    float* deg      = (float*)alloc((size_t)2 * N * 4);  // deg (float) + indeg (int), contiguous
    int*   indeg    = (int*)(deg + N);                   // reused as cursor
    int*   rowstart = (int*)alloc((size_t)(N + 1) * 4);
    int*   bsums    = (int*)alloc(256 * 4);
    int*   csr      = (int*)alloc((size_t)E * 4);
    unsigned short* xb   = (unsigned short*)alloc((size_t)N * H * 2);
    unsigned short* bufH = (unsigned short*)alloc((size_t)N * H * 2);
    unsigned short* bufA = (unsigned short*)alloc((size_t)N * H * 2);
    unsigned short* Wt1  = (unsigned short*)alloc((size_t)H * H * 2);
    unsigned short* Wt2  = (unsigned short*)alloc((size_t)H * H * 2);
    unsigned short* Wht  = (unsigned short*)alloc((size_t)C * H * 2);

    const int nb = cdiv(N, 1024);

    // ---- degrees (both directions, one pass) + CSR by target ----
    hipMemsetAsync(deg, 0, (size_t)2 * N * 4, stream);
    count_both_k<<<cdiv(E, 256), 256, 0, stream>>>(rows, cols, deg, indeg, E);
    scan_block_k<<<nb, 256, 0, stream>>>(indeg, rowstart, bsums, N);
    scan_sums_k<<<1, 256, 0, stream>>>(bsums, nb, rowstart, N, E);
    scan_add_dinv_k<<<cdiv(N, 256), 256, 0, stream>>>(rowstart, indeg, bsums, deg, N);
    fill_csr_k<<<cdiv(E, 256), 256, 0, stream>>>(rows, cols, indeg, csr, E);
    float* dinv = deg;   // finished by scan_add_dinv_k

    // ---- conversions ----
    f2b_k<<<cdiv(N * H / 4, 256), 256, 0, stream>>>(x, xb, N * H / 4);
    prep_weights_k<<<cdiv(147456, 256), 256, 0, stream>>>(W1, W2, Wh, Wt1, Wt2, Wht);

    dim3 g1(cdiv(N, 128), H / 128);
    dim3 gh(cdiv(N, 128), 1);
    const int ggather = cdiv(N, 16) * 8;

    // ---- layer 1 ----
    gemm_mfma_k<128, 0><<<g1, 256, 0, stream>>>(xb, Wt1, b1, dinv, bufH, N, H, H);
    gather_slice_k<<<ggather, 256, 0, stream>>>(rowstart, csr, dinv, bufH, bufA, N);

    // ---- layer 2 ----
    gemm_mfma_k<128, 0><<<g1, 256, 0, stream>>>(bufA, Wt2, b2, dinv, bufH, N, H, H);
    gather_slice_k<<<ggather, 256, 0, stream>>>(rowstart, csr, dinv, bufH, bufA, N);

    // ---- head ----
    gemm_mfma_k<64, 1><<<gh, 256, 0, stream>>>(bufA, Wht, bh, nullptr, out, N, H, C);
}

// Round 6
// 216.721 us; speedup vs baseline: 1.3672x; 1.3672x over previous
//
#include <hip/hip_runtime.h>
#include <hip/hip_bf16.h>

typedef __attribute__((ext_vector_type(8))) short short8;
typedef __attribute__((ext_vector_type(4))) float f32x4;

static inline int cdiv(int a, int b) { return (a + b - 1) / b; }

__device__ inline float bf2f(unsigned short u) {
    union { unsigned int u; float f; } a; a.u = ((unsigned int)u) << 16; return a.f;
}
__device__ inline unsigned short f2bf(float f) {
    union { float f; unsigned int u; } a; a.f = f;
    unsigned int r = a.u + 0x7fff + ((a.u >> 16) & 1);
    return (unsigned short)(r >> 16);
}
__device__ inline void gload_lds16(const void* g, void* l) {
    __builtin_amdgcn_global_load_lds(
        (const __attribute__((address_space(1))) unsigned int*)g,
        (__attribute__((address_space(3))) unsigned int*)l, 16, 0, 0);
}

// ---------------- preprocessing ----------------
__global__ __launch_bounds__(256) void count_both_k(
    const int* __restrict__ rows, const int* __restrict__ cols,
    float* deg, int* indeg, int E)
{
    int e = blockIdx.x * 256 + threadIdx.x;
    if (e < E) {
        atomicAdd(&deg[rows[e]], 1.0f);
        atomicAdd(&indeg[cols[e]], 1);
    }
}

__global__ __launch_bounds__(256) void scan_block_k(
    const int* __restrict__ indeg, int* __restrict__ rowstart, int* __restrict__ bsums, int N)
{
    __shared__ int smem[256];
    int b = blockIdx.x, t = threadIdx.x;
    int base = b * 1024 + t * 4;
    int v0 = (base + 0 < N) ? indeg[base + 0] : 0;
    int v1 = (base + 1 < N) ? indeg[base + 1] : 0;
    int v2 = (base + 2 < N) ? indeg[base + 2] : 0;
    int v3 = (base + 3 < N) ? indeg[base + 3] : 0;
    int s = v0 + v1 + v2 + v3;
    smem[t] = s;
    __syncthreads();
    for (int off = 1; off < 256; off <<= 1) {
        int x = smem[t];
        int y = (t >= off) ? smem[t - off] : 0;
        __syncthreads();
        smem[t] = x + y;
        __syncthreads();
    }
    int excl = smem[t] - s;
    if (base + 0 < N) rowstart[base + 0] = excl;
    if (base + 1 < N) rowstart[base + 1] = excl + v0;
    if (base + 2 < N) rowstart[base + 2] = excl + v0 + v1;
    if (base + 3 < N) rowstart[base + 3] = excl + v0 + v1 + v2;
    if (t == 255) bsums[b] = smem[255];
}

__global__ __launch_bounds__(256) void scan_sums_k(int* bsums, int nb, int* rowstart, int N, int E) {
    __shared__ int smem[256];
    int t = threadIdx.x;
    int v = (t < nb) ? bsums[t] : 0;
    smem[t] = v;
    __syncthreads();
    for (int off = 1; off < 256; off <<= 1) {
        int x = smem[t];
        int y = (t >= off) ? smem[t - off] : 0;
        __syncthreads();
        smem[t] = x + y;
        __syncthreads();
    }
    if (t < nb) bsums[t] = smem[t] - v;
    if (t == 0) rowstart[N] = E;
}

__global__ __launch_bounds__(256) void scan_add_dinv_k(
    int* rowstart, int* cursor, const int* __restrict__ bsums, float* deg, int N)
{
    int i = blockIdx.x * 256 + threadIdx.x;
    if (i < N) {
        int v = rowstart[i] + bsums[i >> 10];
        rowstart[i] = v;
        cursor[i] = v;
        deg[i] = rsqrtf(deg[i] + 1.0f);
    }
}

__global__ __launch_bounds__(256) void fill_csr_k(
    const int* __restrict__ rows, const int* __restrict__ cols,
    int* cursor, int* __restrict__ csr, int E)
{
    int e = blockIdx.x * 256 + threadIdx.x;
    if (e < E) {
        int pos = atomicAdd(&cursor[cols[e]], 1);
        csr[pos] = rows[e];
    }
}

// ---------------- dtype conversion ----------------
__global__ __launch_bounds__(256) void f2b_k(const float* __restrict__ in, unsigned short* __restrict__ out, int n4) {
    int i = blockIdx.x * 256 + threadIdx.x;
    if (i >= n4) return;
    float4 v = ((const float4*)in)[i];
    ushort4 o;
    o.x = f2bf(v.x); o.y = f2bf(v.y); o.z = f2bf(v.z); o.w = f2bf(v.w);
    ((ushort4*)out)[i] = o;
}

__global__ __launch_bounds__(256) void prep_weights_k(
    const float* __restrict__ W1, const float* __restrict__ W2, const float* __restrict__ Wh,
    unsigned short* __restrict__ Wt1, unsigned short* __restrict__ Wt2, unsigned short* __restrict__ Wht)
{
    int idx = blockIdx.x * 256 + threadIdx.x;
    if (idx < 65536) {
        int k = idx >> 8, m = idx & 255;
        Wt1[m * 256 + k] = f2bf(W1[idx]);
    } else if (idx < 131072) {
        int i = idx - 65536;
        int k = i >> 8, m = i & 255;
        Wt2[m * 256 + k] = f2bf(W2[i]);
    } else if (idx < 147456) {
        int i = idx - 131072;
        int k = i >> 6, m = i & 63;    // Wh is 256 x 64
        Wht[m * 256 + k] = f2bf(Wh[i]);
    }
}

// ---------------- MFMA GEMM, 2-phase double-buffered ----------------
template<int BN, int MODE>
__global__ __launch_bounds__(256) void gemm_mfma_k(
    const unsigned short* __restrict__ A, const unsigned short* __restrict__ Wt,
    const float* __restrict__ bias, const float* __restrict__ rowscale,
    void* __restrict__ Cout, int N, int K, int Ncols)
{
    constexpr int NF = BN / 32;
    __shared__ __align__(16) unsigned short As[2][128 * 64];
    __shared__ __align__(16) unsigned short Bs[2][BN * 64];

    const int tid = threadIdx.x;
    const int wid = tid >> 6;
    const int lane = tid & 63;
    const int wr = wid >> 1;
    const int wc = wid & 1;
    const int rowBase = blockIdx.x * 128;
    const int colBase = blockIdx.y * BN;

    f32x4 acc[4][NF];
    #pragma unroll
    for (int m = 0; m < 4; ++m)
        #pragma unroll
        for (int n = 0; n < NF; ++n)
            acc[m][n] = (f32x4)0.0f;

    const int sslot = (lane & 7) ^ (lane >> 3);   // pre-swizzled source slot (m173)

    auto stage = [&](int buf, int k0) {
        #pragma unroll
        for (int it = 0; it < 4; ++it) {
            int ch = wid * 4 + it;
            int r = ch * 8 + (lane >> 3);
            int grow = rowBase + r; if (grow >= N) grow = N - 1;
            gload_lds16(A + (size_t)grow * K + k0 + sslot * 8, (void*)&As[buf][ch * 512]);
        }
        #pragma unroll
        for (int it = 0; it < NF; ++it) {
            int ch = wid * NF + it;
            int c = ch * 8 + (lane >> 3);
            gload_lds16(Wt + (size_t)(colBase + c) * K + k0 + sslot * 8, (void*)&Bs[buf][ch * 512]);
        }
    };

    const int nt = K >> 6;       // 4 for K=256
    stage(0, 0);
    __syncthreads();

    int cur = 0;
    for (int t = 0; t < nt; ++t) {
        if (t + 1 < nt) stage(cur ^ 1, (t + 1) * 64);
        #pragma unroll
        for (int ks = 0; ks < 2; ++ks) {
            short8 af[4];
            #pragma unroll
            for (int m = 0; m < 4; ++m) {
                int R = wr * 64 + m * 16 + (lane & 15);
                int p = (ks * 4 + (lane >> 4)) ^ (R & 7);
                af[m] = *(const short8*)(&As[cur][R * 64 + p * 8]);
            }
            #pragma unroll
            for (int n = 0; n < NF; ++n) {
                int Cc = wc * (BN / 2) + n * 16 + (lane & 15);
                int p = (ks * 4 + (lane >> 4)) ^ (Cc & 7);
                short8 bf = *(const short8*)(&Bs[cur][Cc * 64 + p * 8]);
                #pragma unroll
                for (int m = 0; m < 4; ++m)
                    acc[m][n] = __builtin_amdgcn_mfma_f32_16x16x32_bf16(af[m], bf, acc[m][n], 0, 0, 0);
            }
        }
        if (t + 1 < nt) __syncthreads();
        cur ^= 1;
    }

    float bv[NF];
    int colv[NF];
    #pragma unroll
    for (int n = 0; n < NF; ++n) {
        colv[n] = colBase + wc * (BN / 2) + n * 16 + (lane & 15);
        bv[n] = bias[colv[n]];
    }
    #pragma unroll
    for (int m = 0; m < 4; ++m) {
        #pragma unroll
        for (int q = 0; q < 4; ++q) {
            int row = rowBase + wr * 64 + m * 16 + (lane >> 4) * 4 + q;
            if (row >= N) continue;
            if (MODE == 0) {
                float sc = rowscale[row];
                unsigned short* Cb = (unsigned short*)Cout;
                #pragma unroll
                for (int n = 0; n < NF; ++n)
                    Cb[(size_t)row * Ncols + colv[n]] = f2bf((acc[m][n][q] + bv[n]) * sc);
            } else {
                float* Cf = (float*)Cout;
                #pragma unroll
                for (int n = 0; n < NF; ++n)
                    Cf[(size_t)row * Ncols + colv[n]] = acc[m][n][q] + bv[n];
            }
        }
    }
}

// ---------------- gather aggregate (full 512B rows, 4-deep ILP) ----------------
// one wave per node: out[c] = relu(dinv[c] * (h'[c] + sum_{r->c} h'[r]))
// c forced wave-uniform via readfirstlane -> rowstart/csr become scalar loads.
__global__ __launch_bounds__(256) void gather_agg_k(
    const int* __restrict__ rowstart, const int* __restrict__ csr,
    const float* __restrict__ dinv, const unsigned short* __restrict__ hp,
    unsigned short* __restrict__ out, int N)
{
    int c = __builtin_amdgcn_readfirstlane(blockIdx.x * 4 + (threadIdx.x >> 6));
    if (c >= N) return;
    int lane = threadIdx.x & 63;
    const ushort4* base = (const ushort4*)hp;
    int beg = rowstart[c], end = rowstart[c + 1];

    ushort4 sv = base[(size_t)c * 64 + lane];    // self loop
    float a0 = bf2f(sv.x), a1 = bf2f(sv.y), a2 = bf2f(sv.z), a3 = bf2f(sv.w);

    int e = beg;
    for (; e + 4 <= end; e += 4) {
        int r0 = csr[e + 0], r1 = csr[e + 1], r2 = csr[e + 2], r3 = csr[e + 3];
        ushort4 v0 = base[(size_t)r0 * 64 + lane];
        ushort4 v1 = base[(size_t)r1 * 64 + lane];
        ushort4 v2 = base[(size_t)r2 * 64 + lane];
        ushort4 v3 = base[(size_t)r3 * 64 + lane];
        a0 += bf2f(v0.x) + bf2f(v1.x) + bf2f(v2.x) + bf2f(v3.x);
        a1 += bf2f(v0.y) + bf2f(v1.y) + bf2f(v2.y) + bf2f(v3.y);
        a2 += bf2f(v0.z) + bf2f(v1.z) + bf2f(v2.z) + bf2f(v3.z);
        a3 += bf2f(v0.w) + bf2f(v1.w) + bf2f(v2.w) + bf2f(v3.w);
    }
    for (; e < end; ++e) {
        int r0 = csr[e];
        ushort4 v0 = base[(size_t)r0 * 64 + lane];
        a0 += bf2f(v0.x); a1 += bf2f(v0.y); a2 += bf2f(v0.z); a3 += bf2f(v0.w);
    }

    float sc = dinv[c];
    ushort4 o;
    o.x = f2bf(fmaxf(sc * a0, 0.f));
    o.y = f2bf(fmaxf(sc * a1, 0.f));
    o.z = f2bf(fmaxf(sc * a2, 0.f));
    o.w = f2bf(fmaxf(sc * a3, 0.f));
    ((ushort4*)out)[(size_t)c * 64 + lane] = o;
}

extern "C" void kernel_launch(void* const* d_in, const int* in_sizes, int n_in,
                              void* d_out, int out_size, void* d_ws, size_t ws_size,
                              hipStream_t stream) {
    const float* x  = (const float*)d_in[0];
    const int*  ei  = (const int*)d_in[1];
    const float* W1 = (const float*)d_in[2];
    const float* b1 = (const float*)d_in[3];
    const float* W2 = (const float*)d_in[4];
    const float* b2 = (const float*)d_in[5];
    const float* Wh = (const float*)d_in[6];
    const float* bh = (const float*)d_in[7];
    float* out = (float*)d_out;

    const int N = in_sizes[0] / 256;       // 50000
    const int E = in_sizes[1] / 2;         // 400000
    const int H = 256;
    const int C = 64;
    const int* rows = ei;
    const int* cols = ei + E;

    char* ws = (char*)d_ws;
    size_t off = 0;
    auto alloc = [&](size_t bytes) {
        void* p = ws + off;
        off = (off + bytes + 255) & ~(size_t)255;
        return p;
    };
    float* deg      = (float*)alloc((size_t)2 * N * 4);  // deg (float) + indeg (int)
    int*   indeg    = (int*)(deg + N);                   // reused as cursor
    int*   rowstart = (int*)alloc((size_t)(N + 1) * 4);
    int*   bsums    = (int*)alloc(256 * 4);
    int*   csr      = (int*)alloc((size_t)E * 4);
    unsigned short* xb   = (unsigned short*)alloc((size_t)N * H * 2);
    unsigned short* bufH = (unsigned short*)alloc((size_t)N * H * 2);
    unsigned short* bufA = (unsigned short*)alloc((size_t)N * H * 2);
    unsigned short* Wt1  = (unsigned short*)alloc((size_t)H * H * 2);
    unsigned short* Wt2  = (unsigned short*)alloc((size_t)H * H * 2);
    unsigned short* Wht  = (unsigned short*)alloc((size_t)C * H * 2);

    const int nb = cdiv(N, 1024);

    // ---- degrees + CSR by target ----
    hipMemsetAsync(deg, 0, (size_t)2 * N * 4, stream);
    count_both_k<<<cdiv(E, 256), 256, 0, stream>>>(rows, cols, deg, indeg, E);
    scan_block_k<<<nb, 256, 0, stream>>>(indeg, rowstart, bsums, N);
    scan_sums_k<<<1, 256, 0, stream>>>(bsums, nb, rowstart, N, E);
    scan_add_dinv_k<<<cdiv(N, 256), 256, 0, stream>>>(rowstart, indeg, bsums, deg, N);
    fill_csr_k<<<cdiv(E, 256), 256, 0, stream>>>(rows, cols, indeg, csr, E);
    float* dinv = deg;

    // ---- conversions ----
    f2b_k<<<cdiv(N * H / 4, 256), 256, 0, stream>>>(x, xb, N * H / 4);
    prep_weights_k<<<cdiv(147456, 256), 256, 0, stream>>>(W1, W2, Wh, Wt1, Wt2, Wht);

    dim3 g1(cdiv(N, 128), H / 128);
    dim3 gh(cdiv(N, 128), 1);

    // ---- layer 1 ----
    gemm_mfma_k<128, 0><<<g1, 256, 0, stream>>>(xb, Wt1, b1, dinv, bufH, N, H, H);
    gather_agg_k<<<cdiv(N, 4), 256, 0, stream>>>(rowstart, csr, dinv, bufH, bufA, N);

    // ---- layer 2 ----
    gemm_mfma_k<128, 0><<<g1, 256, 0, stream>>>(bufA, Wt2, b2, dinv, bufH, N, H, H);
    gather_agg_k<<<cdiv(N, 4), 256, 0, stream>>>(rowstart, csr, dinv, bufH, bufA, N);

    // ---- head ----
    gemm_mfma_k<64, 1><<<gh, 256, 0, stream>>>(bufA, Wht, bh, nullptr, out, N, H, C);
}

// Round 7
// 215.241 us; speedup vs baseline: 1.3766x; 1.0069x over previous
//
#include <hip/hip_runtime.h>
#include <hip/hip_bf16.h>

typedef __attribute__((ext_vector_type(8))) short short8;
typedef __attribute__((ext_vector_type(4))) float f32x4;

static inline int cdiv(int a, int b) { return (a + b - 1) / b; }

__device__ inline float bf2f(unsigned short u) {
    union { unsigned int u; float f; } a; a.u = ((unsigned int)u) << 16; return a.f;
}
__device__ inline unsigned short f2bf(float f) {
    union { float f; unsigned int u; } a; a.f = f;
    unsigned int r = a.u + 0x7fff + ((a.u >> 16) & 1);
    return (unsigned short)(r >> 16);
}
__device__ inline void gload_lds16(const void* g, void* l) {
    __builtin_amdgcn_global_load_lds(
        (const __attribute__((address_space(1))) unsigned int*)g,
        (__attribute__((address_space(3))) unsigned int*)l, 16, 0, 0);
}

// ---------------- preprocessing ----------------
// zero deg+indeg (replaces rocclr fillBuffer: 400KB fill was ~39.5us, this is ~2us)
__global__ __launch_bounds__(256) void zero_k(float4* p, int n4) {
    int i = blockIdx.x * 256 + threadIdx.x;
    if (i < n4) p[i] = make_float4(0.f, 0.f, 0.f, 0.f);
}

__global__ __launch_bounds__(256) void count_both_k(
    const int* __restrict__ rows, const int* __restrict__ cols,
    float* deg, int* indeg, int E)
{
    int e = blockIdx.x * 256 + threadIdx.x;
    if (e < E) {
        atomicAdd(&deg[rows[e]], 1.0f);
        atomicAdd(&indeg[cols[e]], 1);
    }
}

__global__ __launch_bounds__(256) void scan_block_k(
    const int* __restrict__ indeg, int* __restrict__ rowstart, int* __restrict__ bsums, int N)
{
    __shared__ int smem[256];
    int b = blockIdx.x, t = threadIdx.x;
    int base = b * 1024 + t * 4;
    int v0 = (base + 0 < N) ? indeg[base + 0] : 0;
    int v1 = (base + 1 < N) ? indeg[base + 1] : 0;
    int v2 = (base + 2 < N) ? indeg[base + 2] : 0;
    int v3 = (base + 3 < N) ? indeg[base + 3] : 0;
    int s = v0 + v1 + v2 + v3;
    smem[t] = s;
    __syncthreads();
    for (int off = 1; off < 256; off <<= 1) {
        int x = smem[t];
        int y = (t >= off) ? smem[t - off] : 0;
        __syncthreads();
        smem[t] = x + y;
        __syncthreads();
    }
    int excl = smem[t] - s;
    if (base + 0 < N) rowstart[base + 0] = excl;
    if (base + 1 < N) rowstart[base + 1] = excl + v0;
    if (base + 2 < N) rowstart[base + 2] = excl + v0 + v1;
    if (base + 3 < N) rowstart[base + 3] = excl + v0 + v1 + v2;
    if (t == 255) bsums[b] = smem[255];
}

__global__ __launch_bounds__(256) void scan_sums_k(int* bsums, int nb, int* rowstart, int N, int E) {
    __shared__ int smem[256];
    int t = threadIdx.x;
    int v = (t < nb) ? bsums[t] : 0;
    smem[t] = v;
    __syncthreads();
    for (int off = 1; off < 256; off <<= 1) {
        int x = smem[t];
        int y = (t >= off) ? smem[t - off] : 0;
        __syncthreads();
        smem[t] = x + y;
        __syncthreads();
    }
    if (t < nb) bsums[t] = smem[t] - v;
    if (t == 0) rowstart[N] = E;
}

__global__ __launch_bounds__(256) void scan_add_dinv_k(
    int* rowstart, int* cursor, const int* __restrict__ bsums, float* deg, int N)
{
    int i = blockIdx.x * 256 + threadIdx.x;
    if (i < N) {
        int v = rowstart[i] + bsums[i >> 10];
        rowstart[i] = v;
        cursor[i] = v;
        deg[i] = rsqrtf(deg[i] + 1.0f);
    }
}

__global__ __launch_bounds__(256) void fill_csr_k(
    const int* __restrict__ rows, const int* __restrict__ cols,
    int* cursor, int* __restrict__ csr, int E)
{
    int e = blockIdx.x * 256 + threadIdx.x;
    if (e < E) {
        int pos = atomicAdd(&cursor[cols[e]], 1);
        csr[pos] = rows[e];
    }
}

// ---------------- dtype conversion ----------------
__global__ __launch_bounds__(256) void f2b_k(const float* __restrict__ in, unsigned short* __restrict__ out, int n4) {
    int i = blockIdx.x * 256 + threadIdx.x;
    if (i >= n4) return;
    float4 v = ((const float4*)in)[i];
    ushort4 o;
    o.x = f2bf(v.x); o.y = f2bf(v.y); o.z = f2bf(v.z); o.w = f2bf(v.w);
    ((ushort4*)out)[i] = o;
}

__global__ __launch_bounds__(256) void prep_weights_k(
    const float* __restrict__ W1, const float* __restrict__ W2, const float* __restrict__ Wh,
    unsigned short* __restrict__ Wt1, unsigned short* __restrict__ Wt2, unsigned short* __restrict__ Wht)
{
    int idx = blockIdx.x * 256 + threadIdx.x;
    if (idx < 65536) {
        int k = idx >> 8, m = idx & 255;
        Wt1[m * 256 + k] = f2bf(W1[idx]);
    } else if (idx < 131072) {
        int i = idx - 65536;
        int k = i >> 8, m = i & 255;
        Wt2[m * 256 + k] = f2bf(W2[i]);
    } else if (idx < 147456) {
        int i = idx - 131072;
        int k = i >> 6, m = i & 63;    // Wh is 256 x 64
        Wht[m * 256 + k] = f2bf(Wh[i]);
    }
}

// ---------------- MFMA GEMM, 2-phase double-buffered ----------------
template<int BN, int MODE>
__global__ __launch_bounds__(256) void gemm_mfma_k(
    const unsigned short* __restrict__ A, const unsigned short* __restrict__ Wt,
    const float* __restrict__ bias, const float* __restrict__ rowscale,
    void* __restrict__ Cout, int N, int K, int Ncols)
{
    constexpr int NF = BN / 32;
    __shared__ __align__(16) unsigned short As[2][128 * 64];
    __shared__ __align__(16) unsigned short Bs[2][BN * 64];

    const int tid = threadIdx.x;
    const int wid = tid >> 6;
    const int lane = tid & 63;
    const int wr = wid >> 1;
    const int wc = wid & 1;
    const int rowBase = blockIdx.x * 128;
    const int colBase = blockIdx.y * BN;

    f32x4 acc[4][NF];
    #pragma unroll
    for (int m = 0; m < 4; ++m)
        #pragma unroll
        for (int n = 0; n < NF; ++n)
            acc[m][n] = (f32x4)0.0f;

    const int sslot = (lane & 7) ^ (lane >> 3);   // pre-swizzled source slot (m173)

    auto stage = [&](int buf, int k0) {
        #pragma unroll
        for (int it = 0; it < 4; ++it) {
            int ch = wid * 4 + it;
            int r = ch * 8 + (lane >> 3);
            int grow = rowBase + r; if (grow >= N) grow = N - 1;
            gload_lds16(A + (size_t)grow * K + k0 + sslot * 8, (void*)&As[buf][ch * 512]);
        }
        #pragma unroll
        for (int it = 0; it < NF; ++it) {
            int ch = wid * NF + it;
            int c = ch * 8 + (lane >> 3);
            gload_lds16(Wt + (size_t)(colBase + c) * K + k0 + sslot * 8, (void*)&Bs[buf][ch * 512]);
        }
    };

    const int nt = K >> 6;       // 4 for K=256
    stage(0, 0);
    __syncthreads();

    int cur = 0;
    for (int t = 0; t < nt; ++t) {
        if (t + 1 < nt) stage(cur ^ 1, (t + 1) * 64);
        #pragma unroll
        for (int ks = 0; ks < 2; ++ks) {
            short8 af[4];
            #pragma unroll
            for (int m = 0; m < 4; ++m) {
                int R = wr * 64 + m * 16 + (lane & 15);
                int p = (ks * 4 + (lane >> 4)) ^ (R & 7);
                af[m] = *(const short8*)(&As[cur][R * 64 + p * 8]);
            }
            #pragma unroll
            for (int n = 0; n < NF; ++n) {
                int Cc = wc * (BN / 2) + n * 16 + (lane & 15);
                int p = (ks * 4 + (lane >> 4)) ^ (Cc & 7);
                short8 bf = *(const short8*)(&Bs[cur][Cc * 64 + p * 8]);
                #pragma unroll
                for (int m = 0; m < 4; ++m)
                    acc[m][n] = __builtin_amdgcn_mfma_f32_16x16x32_bf16(af[m], bf, acc[m][n], 0, 0, 0);
            }
        }
        if (t + 1 < nt) __syncthreads();
        cur ^= 1;
    }

    float bv[NF];
    int colv[NF];
    #pragma unroll
    for (int n = 0; n < NF; ++n) {
        colv[n] = colBase + wc * (BN / 2) + n * 16 + (lane & 15);
        bv[n] = bias[colv[n]];
    }
    #pragma unroll
    for (int m = 0; m < 4; ++m) {
        #pragma unroll
        for (int q = 0; q < 4; ++q) {
            int row = rowBase + wr * 64 + m * 16 + (lane >> 4) * 4 + q;
            if (row >= N) continue;
            if (MODE == 0) {
                float sc = rowscale[row];
                unsigned short* Cb = (unsigned short*)Cout;
                #pragma unroll
                for (int n = 0; n < NF; ++n)
                    Cb[(size_t)row * Ncols + colv[n]] = f2bf((acc[m][n][q] + bv[n]) * sc);
            } else {
                float* Cf = (float*)Cout;
                #pragma unroll
                for (int n = 0; n < NF; ++n)
                    Cf[(size_t)row * Ncols + colv[n]] = acc[m][n][q] + bv[n];
            }
        }
    }
}

// ---------------- gather aggregate (full 512B rows, 8-deep ILP) ----------------
__global__ __launch_bounds__(256) void gather_agg_k(
    const int* __restrict__ rowstart, const int* __restrict__ csr,
    const float* __restrict__ dinv, const unsigned short* __restrict__ hp,
    unsigned short* __restrict__ out, int N)
{
    int c = __builtin_amdgcn_readfirstlane(blockIdx.x * 4 + (threadIdx.x >> 6));
    if (c >= N) return;
    int lane = threadIdx.x & 63;
    const ushort4* base = (const ushort4*)hp;
    int beg = rowstart[c], end = rowstart[c + 1];

    ushort4 sv = base[(size_t)c * 64 + lane];    // self loop
    float a0 = bf2f(sv.x), a1 = bf2f(sv.y), a2 = bf2f(sv.z), a3 = bf2f(sv.w);

    int e = beg;
    for (; e + 8 <= end; e += 8) {
        ushort4 v0 = base[(size_t)csr[e + 0] * 64 + lane];
        ushort4 v1 = base[(size_t)csr[e + 1] * 64 + lane];
        ushort4 v2 = base[(size_t)csr[e + 2] * 64 + lane];
        ushort4 v3 = base[(size_t)csr[e + 3] * 64 + lane];
        ushort4 v4 = base[(size_t)csr[e + 4] * 64 + lane];
        ushort4 v5 = base[(size_t)csr[e + 5] * 64 + lane];
        ushort4 v6 = base[(size_t)csr[e + 6] * 64 + lane];
        ushort4 v7 = base[(size_t)csr[e + 7] * 64 + lane];
        a0 += bf2f(v0.x) + bf2f(v1.x) + bf2f(v2.x) + bf2f(v3.x)
            + bf2f(v4.x) + bf2f(v5.x) + bf2f(v6.x) + bf2f(v7.x);
        a1 += bf2f(v0.y) + bf2f(v1.y) + bf2f(v2.y) + bf2f(v3.y)
            + bf2f(v4.y) + bf2f(v5.y) + bf2f(v6.y) + bf2f(v7.y);
        a2 += bf2f(v0.z) + bf2f(v1.z) + bf2f(v2.z) + bf2f(v3.z)
            + bf2f(v4.z) + bf2f(v5.z) + bf2f(v6.z) + bf2f(v7.z);
        a3 += bf2f(v0.w) + bf2f(v1.w) + bf2f(v2.w) + bf2f(v3.w)
            + bf2f(v4.w) + bf2f(v5.w) + bf2f(v6.w) + bf2f(v7.w);
    }
    for (; e + 4 <= end; e += 4) {
        ushort4 v0 = base[(size_t)csr[e + 0] * 64 + lane];
        ushort4 v1 = base[(size_t)csr[e + 1] * 64 + lane];
        ushort4 v2 = base[(size_t)csr[e + 2] * 64 + lane];
        ushort4 v3 = base[(size_t)csr[e + 3] * 64 + lane];
        a0 += bf2f(v0.x) + bf2f(v1.x) + bf2f(v2.x) + bf2f(v3.x);
        a1 += bf2f(v0.y) + bf2f(v1.y) + bf2f(v2.y) + bf2f(v3.y);
        a2 += bf2f(v0.z) + bf2f(v1.z) + bf2f(v2.z) + bf2f(v3.z);
        a3 += bf2f(v0.w) + bf2f(v1.w) + bf2f(v2.w) + bf2f(v3.w);
    }
    for (; e < end; ++e) {
        ushort4 v0 = base[(size_t)csr[e] * 64 + lane];
        a0 += bf2f(v0.x); a1 += bf2f(v0.y); a2 += bf2f(v0.z); a3 += bf2f(v0.w);
    }

    float sc = dinv[c];
    ushort4 o;
    o.x = f2bf(fmaxf(sc * a0, 0.f));
    o.y = f2bf(fmaxf(sc * a1, 0.f));
    o.z = f2bf(fmaxf(sc * a2, 0.f));
    o.w = f2bf(fmaxf(sc * a3, 0.f));
    ((ushort4*)out)[(size_t)c * 64 + lane] = o;
}

extern "C" void kernel_launch(void* const* d_in, const int* in_sizes, int n_in,
                              void* d_out, int out_size, void* d_ws, size_t ws_size,
                              hipStream_t stream) {
    const float* x  = (const float*)d_in[0];
    const int*  ei  = (const int*)d_in[1];
    const float* W1 = (const float*)d_in[2];
    const float* b1 = (const float*)d_in[3];
    const float* W2 = (const float*)d_in[4];
    const float* b2 = (const float*)d_in[5];
    const float* Wh = (const float*)d_in[6];
    const float* bh = (const float*)d_in[7];
    float* out = (float*)d_out;

    const int N = in_sizes[0] / 256;       // 50000
    const int E = in_sizes[1] / 2;         // 400000
    const int H = 256;
    const int C = 64;
    const int* rows = ei;
    const int* cols = ei + E;

    char* ws = (char*)d_ws;
    size_t off = 0;
    auto alloc = [&](size_t bytes) {
        void* p = ws + off;
        off = (off + bytes + 255) & ~(size_t)255;
        return p;
    };
    float* deg      = (float*)alloc((size_t)2 * N * 4);  // deg (float) + indeg (int)
    int*   indeg    = (int*)(deg + N);                   // reused as cursor
    int*   rowstart = (int*)alloc((size_t)(N + 1) * 4);
    int*   bsums    = (int*)alloc(256 * 4);
    int*   csr      = (int*)alloc((size_t)E * 4);
    unsigned short* xb   = (unsigned short*)alloc((size_t)N * H * 2);
    unsigned short* bufH = (unsigned short*)alloc((size_t)N * H * 2);
    unsigned short* bufA = (unsigned short*)alloc((size_t)N * H * 2);
    unsigned short* Wt1  = (unsigned short*)alloc((size_t)H * H * 2);
    unsigned short* Wt2  = (unsigned short*)alloc((size_t)H * H * 2);
    unsigned short* Wht  = (unsigned short*)alloc((size_t)C * H * 2);

    const int nb = cdiv(N, 1024);

    // ---- degrees + CSR by target ----
    zero_k<<<cdiv(2 * N / 4, 256), 256, 0, stream>>>((float4*)deg, 2 * N / 4);
    count_both_k<<<cdiv(E, 256), 256, 0, stream>>>(rows, cols, deg, indeg, E);
    scan_block_k<<<nb, 256, 0, stream>>>(indeg, rowstart, bsums, N);
    scan_sums_k<<<1, 256, 0, stream>>>(bsums, nb, rowstart, N, E);
    scan_add_dinv_k<<<cdiv(N, 256), 256, 0, stream>>>(rowstart, indeg, bsums, deg, N);
    fill_csr_k<<<cdiv(E, 256), 256, 0, stream>>>(rows, cols, indeg, csr, E);
    float* dinv = deg;

    // ---- conversions ----
    f2b_k<<<cdiv(N * H / 4, 256), 256, 0, stream>>>(x, xb, N * H / 4);
    prep_weights_k<<<cdiv(147456, 256), 256, 0, stream>>>(W1, W2, Wh, Wt1, Wt2, Wht);

    dim3 g1(cdiv(N, 128), H / 128);
    dim3 gh(cdiv(N, 128), 1);

    // ---- layer 1 ----
    gemm_mfma_k<128, 0><<<g1, 256, 0, stream>>>(xb, Wt1, b1, dinv, bufH, N, H, H);
    gather_agg_k<<<cdiv(N, 4), 256, 0, stream>>>(rowstart, csr, dinv, bufH, bufA, N);

    // ---- layer 2 ----
    gemm_mfma_k<128, 0><<<g1, 256, 0, stream>>>(bufA, Wt2, b2, dinv, bufH, N, H, H);
    gather_agg_k<<<cdiv(N, 4), 256, 0, stream>>>(rowstart, csr, dinv, bufH, bufA, N);

    // ---- head ----
    gemm_mfma_k<64, 1><<<gh, 256, 0, stream>>>(bufA, Wht, bh, nullptr, out, N, H, C);
}

// Round 8
// 206.062 us; speedup vs baseline: 1.4380x; 1.0445x over previous
//
#include <hip/hip_runtime.h>
#include <hip/hip_bf16.h>

typedef __attribute__((ext_vector_type(8))) short short8;
typedef __attribute__((ext_vector_type(4))) float f32x4;

static inline int cdiv(int a, int b) { return (a + b - 1) / b; }

__device__ inline float bf2f(unsigned short u) {
    union { unsigned int u; float f; } a; a.u = ((unsigned int)u) << 16; return a.f;
}
__device__ inline unsigned short f2bf(float f) {
    union { float f; unsigned int u; } a; a.f = f;
    unsigned int r = a.u + 0x7fff + ((a.u >> 16) & 1);
    return (unsigned short)(r >> 16);
}
__device__ inline void gload_lds16(const void* g, void* l) {
    __builtin_amdgcn_global_load_lds(
        (const __attribute__((address_space(1))) unsigned int*)g,
        (__attribute__((address_space(3))) unsigned int*)l, 16, 0, 0);
}

// ---------------- preprocessing ----------------
__global__ __launch_bounds__(256) void count_both_k(
    const int* __restrict__ rows, const int* __restrict__ cols,
    float* deg, int* indeg, int E)
{
    int e = blockIdx.x * 256 + threadIdx.x;
    if (e < E) {
        atomicAdd(&deg[rows[e]], 1.0f);
        atomicAdd(&indeg[cols[e]], 1);
    }
}

__global__ __launch_bounds__(256) void scan_block_k(
    const int* __restrict__ indeg, int* __restrict__ rowstart, int* __restrict__ bsums, int N)
{
    __shared__ int smem[256];
    int b = blockIdx.x, t = threadIdx.x;
    int base = b * 1024 + t * 4;
    int v0 = (base + 0 < N) ? indeg[base + 0] : 0;
    int v1 = (base + 1 < N) ? indeg[base + 1] : 0;
    int v2 = (base + 2 < N) ? indeg[base + 2] : 0;
    int v3 = (base + 3 < N) ? indeg[base + 3] : 0;
    int s = v0 + v1 + v2 + v3;
    smem[t] = s;
    __syncthreads();
    for (int off = 1; off < 256; off <<= 1) {
        int x = smem[t];
        int y = (t >= off) ? smem[t - off] : 0;
        __syncthreads();
        smem[t] = x + y;
        __syncthreads();
    }
    int excl = smem[t] - s;
    if (base + 0 < N) rowstart[base + 0] = excl;
    if (base + 1 < N) rowstart[base + 1] = excl + v0;
    if (base + 2 < N) rowstart[base + 2] = excl + v0 + v1;
    if (base + 3 < N) rowstart[base + 3] = excl + v0 + v1 + v2;
    if (t == 255) bsums[b] = smem[255];
}

__global__ __launch_bounds__(256) void scan_sums_k(int* bsums, int nb, int* rowstart, int N, int E) {
    __shared__ int smem[256];
    int t = threadIdx.x;
    int v = (t < nb) ? bsums[t] : 0;
    smem[t] = v;
    __syncthreads();
    for (int off = 1; off < 256; off <<= 1) {
        int x = smem[t];
        int y = (t >= off) ? smem[t - off] : 0;
        __syncthreads();
        smem[t] = x + y;
        __syncthreads();
    }
    if (t < nb) bsums[t] = smem[t] - v;
    if (t == 0) rowstart[N] = E;
}

__global__ __launch_bounds__(256) void scan_add_dinv_k(
    int* rowstart, int* cursor, const int* __restrict__ bsums, float* deg, int N)
{
    int i = blockIdx.x * 256 + threadIdx.x;
    if (i < N) {
        int v = rowstart[i] + bsums[i >> 10];
        rowstart[i] = v;
        cursor[i] = v;
        deg[i] = rsqrtf(deg[i] + 1.0f);
    }
}

__global__ __launch_bounds__(256) void fill_csr_k(
    const int* __restrict__ rows, const int* __restrict__ cols,
    int* cursor, int* __restrict__ csr, int E)
{
    int e = blockIdx.x * 256 + threadIdx.x;
    if (e < E) {
        int pos = atomicAdd(&cursor[cols[e]], 1);
        csr[pos] = rows[e];
    }
}

// weight transposes (to bf16 Wt[m][k]) + zero of deg/indeg counters, one launch
__global__ __launch_bounds__(256) void prep_weights_zero_k(
    const float* __restrict__ W1, const float* __restrict__ W2, const float* __restrict__ Wh,
    unsigned short* __restrict__ Wt1, unsigned short* __restrict__ Wt2, unsigned short* __restrict__ Wht,
    float4* __restrict__ zp, int nz4)
{
    int idx = blockIdx.x * 256 + threadIdx.x;
    if (idx < nz4) zp[idx] = make_float4(0.f, 0.f, 0.f, 0.f);
    if (idx < 65536) {
        int k = idx >> 8, m = idx & 255;
        Wt1[m * 256 + k] = f2bf(W1[idx]);
    } else if (idx < 131072) {
        int i = idx - 65536;
        int k = i >> 8, m = i & 255;
        Wt2[m * 256 + k] = f2bf(W2[i]);
    } else if (idx < 147456) {
        int i = idx - 131072;
        int k = i >> 6, m = i & 63;    // Wh is 256 x 64
        Wht[m * 256 + k] = f2bf(Wh[i]);
    }
}

// ---------------- MFMA GEMM, 2-phase double-buffered ----------------
// ASRC 0: A is bf16, staged via global_load_lds.
// ASRC 1: A is fp32, staged global->reg (issued pre-MFMA), cvt+ds_write post-MFMA (T14).
// Both produce the identical swizzled LDS layout; MFMA side untouched.
template<int BN, int MODE, int ASRC>
__global__ __launch_bounds__(256) void gemm_mfma_k(
    const void* __restrict__ Asrc, const unsigned short* __restrict__ Wt,
    const float* __restrict__ bias, const float* __restrict__ rowscale,
    void* __restrict__ Cout, int N, int K, int Ncols)
{
    constexpr int NF = BN / 32;
    __shared__ __align__(16) unsigned short As[2][128 * 64];
    __shared__ __align__(16) unsigned short Bs[2][BN * 64];

    const unsigned short* Ab = (const unsigned short*)Asrc;
    const float* Af = (const float*)Asrc;

    const int tid = threadIdx.x;
    const int wid = tid >> 6;
    const int lane = tid & 63;
    const int wr = wid >> 1;
    const int wc = wid & 1;
    const int rowBase = blockIdx.x * 128;
    const int colBase = blockIdx.y * BN;

    f32x4 acc[4][NF];
    #pragma unroll
    for (int m = 0; m < 4; ++m)
        #pragma unroll
        for (int n = 0; n < NF; ++n)
            acc[m][n] = (f32x4)0.0f;

    const int sslot = (lane & 7) ^ (lane >> 3);   // pre-swizzled source slot (m173)

    float4 areg[4][2];   // ASRC==1 staging regs (static-indexed, unrolled)

    auto stageA_g = [&](int buf, int k0) {
        #pragma unroll
        for (int it = 0; it < 4; ++it) {
            int ch = wid * 4 + it;
            int r = ch * 8 + (lane >> 3);
            int grow = rowBase + r; if (grow >= N) grow = N - 1;
            gload_lds16(Ab + (size_t)grow * K + k0 + sslot * 8, (void*)&As[buf][ch * 512]);
        }
    };
    auto issueA = [&](int k0) {
        #pragma unroll
        for (int it = 0; it < 4; ++it) {
            int ch = wid * 4 + it;
            int r = ch * 8 + (lane >> 3);
            int grow = rowBase + r; if (grow >= N) grow = N - 1;
            const float* src = Af + (size_t)grow * K + k0 + sslot * 8;
            areg[it][0] = *(const float4*)src;
            areg[it][1] = *(const float4*)(src + 4);
        }
    };
    auto writeA = [&](int buf) {
        #pragma unroll
        for (int it = 0; it < 4; ++it) {
            int ch = wid * 4 + it;
            short8 w;
            w[0] = (short)f2bf(areg[it][0].x); w[1] = (short)f2bf(areg[it][0].y);
            w[2] = (short)f2bf(areg[it][0].z); w[3] = (short)f2bf(areg[it][0].w);
            w[4] = (short)f2bf(areg[it][1].x); w[5] = (short)f2bf(areg[it][1].y);
            w[6] = (short)f2bf(areg[it][1].z); w[7] = (short)f2bf(areg[it][1].w);
            *(short8*)&As[buf][ch * 512 + lane * 8] = w;
        }
    };
    auto stageB = [&](int buf, int k0) {
        #pragma unroll
        for (int it = 0; it < NF; ++it) {
            int ch = wid * NF + it;
            int c = ch * 8 + (lane >> 3);
            gload_lds16(Wt + (size_t)(colBase + c) * K + k0 + sslot * 8, (void*)&Bs[buf][ch * 512]);
        }
    };

    const int nt = K >> 6;       // 4 for K=256
    if constexpr (ASRC == 0) {
        stageA_g(0, 0);
        stageB(0, 0);
    } else {
        issueA(0);
        stageB(0, 0);
        writeA(0);
    }
    __syncthreads();

    int cur = 0;
    for (int t = 0; t < nt; ++t) {
        if (t + 1 < nt) {
            if constexpr (ASRC == 0) stageA_g(cur ^ 1, (t + 1) * 64);
            else issueA((t + 1) * 64);
            stageB(cur ^ 1, (t + 1) * 64);
        }
        #pragma unroll
        for (int ks = 0; ks < 2; ++ks) {
            short8 af[4];
            #pragma unroll
            for (int m = 0; m < 4; ++m) {
                int R = wr * 64 + m * 16 + (lane & 15);
                int p = (ks * 4 + (lane >> 4)) ^ (R & 7);
                af[m] = *(const short8*)(&As[cur][R * 64 + p * 8]);
            }
            #pragma unroll
            for (int n = 0; n < NF; ++n) {
                int Cc = wc * (BN / 2) + n * 16 + (lane & 15);
                int p = (ks * 4 + (lane >> 4)) ^ (Cc & 7);
                short8 bf = *(const short8*)(&Bs[cur][Cc * 64 + p * 8]);
                #pragma unroll
                for (int m = 0; m < 4; ++m)
                    acc[m][n] = __builtin_amdgcn_mfma_f32_16x16x32_bf16(af[m], bf, acc[m][n], 0, 0, 0);
            }
        }
        if (t + 1 < nt) {
            if constexpr (ASRC == 1) writeA(cur ^ 1);  // HBM latency hidden under MFMA
            __syncthreads();
        }
        cur ^= 1;
    }

    // epilogue: C/D layout col=lane&15, row=(lane>>4)*4+q  [m89-verified]
    float bv[NF];
    int colv[NF];
    #pragma unroll
    for (int n = 0; n < NF; ++n) {
        colv[n] = colBase + wc * (BN / 2) + n * 16 + (lane & 15);
        bv[n] = bias[colv[n]];
    }
    #pragma unroll
    for (int m = 0; m < 4; ++m) {
        #pragma unroll
        for (int q = 0; q < 4; ++q) {
            int row = rowBase + wr * 64 + m * 16 + (lane >> 4) * 4 + q;
            if (row >= N) continue;
            if (MODE == 0) {
                float sc = rowscale[row];
                unsigned short* Cb = (unsigned short*)Cout;
                #pragma unroll
                for (int n = 0; n < NF; ++n)
                    Cb[(size_t)row * Ncols + colv[n]] = f2bf((acc[m][n][q] + bv[n]) * sc);
            } else {
                float* Cf = (float*)Cout;
                #pragma unroll
                for (int n = 0; n < NF; ++n)
                    Cf[(size_t)row * Ncols + colv[n]] = acc[m][n][q] + bv[n];
            }
        }
    }
}

// ---------------- gather aggregate (full 512B rows, 8-deep ILP) ----------------
__global__ __launch_bounds__(256) void gather_agg_k(
    const int* __restrict__ rowstart, const int* __restrict__ csr,
    const float* __restrict__ dinv, const unsigned short* __restrict__ hp,
    unsigned short* __restrict__ out, int N)
{
    int c = __builtin_amdgcn_readfirstlane(blockIdx.x * 4 + (threadIdx.x >> 6));
    if (c >= N) return;
    int lane = threadIdx.x & 63;
    const ushort4* base = (const ushort4*)hp;
    int beg = rowstart[c], end = rowstart[c + 1];

    ushort4 sv = base[(size_t)c * 64 + lane];    // self loop
    float a0 = bf2f(sv.x), a1 = bf2f(sv.y), a2 = bf2f(sv.z), a3 = bf2f(sv.w);

    int e = beg;
    for (; e + 8 <= end; e += 8) {
        ushort4 v0 = base[(size_t)csr[e + 0] * 64 + lane];
        ushort4 v1 = base[(size_t)csr[e + 1] * 64 + lane];
        ushort4 v2 = base[(size_t)csr[e + 2] * 64 + lane];
        ushort4 v3 = base[(size_t)csr[e + 3] * 64 + lane];
        ushort4 v4 = base[(size_t)csr[e + 4] * 64 + lane];
        ushort4 v5 = base[(size_t)csr[e + 5] * 64 + lane];
        ushort4 v6 = base[(size_t)csr[e + 6] * 64 + lane];
        ushort4 v7 = base[(size_t)csr[e + 7] * 64 + lane];
        a0 += bf2f(v0.x) + bf2f(v1.x) + bf2f(v2.x) + bf2f(v3.x)
            + bf2f(v4.x) + bf2f(v5.x) + bf2f(v6.x) + bf2f(v7.x);
        a1 += bf2f(v0.y) + bf2f(v1.y) + bf2f(v2.y) + bf2f(v3.y)
            + bf2f(v4.y) + bf2f(v5.y) + bf2f(v6.y) + bf2f(v7.y);
        a2 += bf2f(v0.z) + bf2f(v1.z) + bf2f(v2.z) + bf2f(v3.z)
            + bf2f(v4.z) + bf2f(v5.z) + bf2f(v6.z) + bf2f(v7.z);
        a3 += bf2f(v0.w) + bf2f(v1.w) + bf2f(v2.w) + bf2f(v3.w)
            + bf2f(v4.w) + bf2f(v5.w) + bf2f(v6.w) + bf2f(v7.w);
    }
    for (; e + 4 <= end; e += 4) {
        ushort4 v0 = base[(size_t)csr[e + 0] * 64 + lane];
        ushort4 v1 = base[(size_t)csr[e + 1] * 64 + lane];
        ushort4 v2 = base[(size_t)csr[e + 2] * 64 + lane];
        ushort4 v3 = base[(size_t)csr[e + 3] * 64 + lane];
        a0 += bf2f(v0.x) + bf2f(v1.x) + bf2f(v2.x) + bf2f(v3.x);
        a1 += bf2f(v0.y) + bf2f(v1.y) + bf2f(v2.y) + bf2f(v3.y);
        a2 += bf2f(v0.z) + bf2f(v1.z) + bf2f(v2.z) + bf2f(v3.z);
        a3 += bf2f(v0.w) + bf2f(v1.w) + bf2f(v2.w) + bf2f(v3.w);
    }
    for (; e < end; ++e) {
        ushort4 v0 = base[(size_t)csr[e] * 64 + lane];
        a0 += bf2f(v0.x); a1 += bf2f(v0.y); a2 += bf2f(v0.z); a3 += bf2f(v0.w);
    }

    float sc = dinv[c];
    ushort4 o;
    o.x = f2bf(fmaxf(sc * a0, 0.f));
    o.y = f2bf(fmaxf(sc * a1, 0.f));
    o.z = f2bf(fmaxf(sc * a2, 0.f));
    o.w = f2bf(fmaxf(sc * a3, 0.f));
    ((ushort4*)out)[(size_t)c * 64 + lane] = o;
}

extern "C" void kernel_launch(void* const* d_in, const int* in_sizes, int n_in,
                              void* d_out, int out_size, void* d_ws, size_t ws_size,
                              hipStream_t stream) {
    const float* x  = (const float*)d_in[0];
    const int*  ei  = (const int*)d_in[1];
    const float* W1 = (const float*)d_in[2];
    const float* b1 = (const float*)d_in[3];
    const float* W2 = (const float*)d_in[4];
    const float* b2 = (const float*)d_in[5];
    const float* Wh = (const float*)d_in[6];
    const float* bh = (const float*)d_in[7];
    float* out = (float*)d_out;

    const int N = in_sizes[0] / 256;       // 50000
    const int E = in_sizes[1] / 2;         // 400000
    const int H = 256;
    const int C = 64;
    const int* rows = ei;
    const int* cols = ei + E;

    char* ws = (char*)d_ws;
    size_t off = 0;
    auto alloc = [&](size_t bytes) {
        void* p = ws + off;
        off = (off + bytes + 255) & ~(size_t)255;
        return p;
    };
    float* deg      = (float*)alloc((size_t)2 * N * 4);  // deg (float) + indeg (int)
    int*   indeg    = (int*)(deg + N);                   // reused as cursor
    int*   rowstart = (int*)alloc((size_t)(N + 1) * 4);
    int*   bsums    = (int*)alloc(256 * 4);
    int*   csr      = (int*)alloc((size_t)E * 4);
    unsigned short* bufH = (unsigned short*)alloc((size_t)N * H * 2);
    unsigned short* bufA = (unsigned short*)alloc((size_t)N * H * 2);
    unsigned short* Wt1  = (unsigned short*)alloc((size_t)H * H * 2);
    unsigned short* Wt2  = (unsigned short*)alloc((size_t)H * H * 2);
    unsigned short* Wht  = (unsigned short*)alloc((size_t)C * H * 2);

    const int nb = cdiv(N, 1024);

    // ---- weights + counter-zero (one launch), then degrees + CSR ----
    prep_weights_zero_k<<<cdiv(147456, 256), 256, 0, stream>>>(
        W1, W2, Wh, Wt1, Wt2, Wht, (float4*)deg, 2 * N / 4);
    count_both_k<<<cdiv(E, 256), 256, 0, stream>>>(rows, cols, deg, indeg, E);
    scan_block_k<<<nb, 256, 0, stream>>>(indeg, rowstart, bsums, N);
    scan_sums_k<<<1, 256, 0, stream>>>(bsums, nb, rowstart, N, E);
    scan_add_dinv_k<<<cdiv(N, 256), 256, 0, stream>>>(rowstart, indeg, bsums, deg, N);
    fill_csr_k<<<cdiv(E, 256), 256, 0, stream>>>(rows, cols, indeg, csr, E);
    float* dinv = deg;

    dim3 g1(cdiv(N, 128), H / 128);
    dim3 gh(cdiv(N, 128), 1);

    // ---- layer 1 (reads fp32 x directly; conversion fused into staging) ----
    gemm_mfma_k<128, 0, 1><<<g1, 256, 0, stream>>>(x, Wt1, b1, dinv, bufH, N, H, H);
    gather_agg_k<<<cdiv(N, 4), 256, 0, stream>>>(rowstart, csr, dinv, bufH, bufA, N);

    // ---- layer 2 ----
    gemm_mfma_k<128, 0, 0><<<g1, 256, 0, stream>>>(bufA, Wt2, b2, dinv, bufH, N, H, H);
    gather_agg_k<<<cdiv(N, 4), 256, 0, stream>>>(rowstart, csr, dinv, bufH, bufA, N);

    // ---- head ----
    gemm_mfma_k<64, 1, 0><<<gh, 256, 0, stream>>>(bufA, Wht, bh, nullptr, out, N, H, C);
}

// Round 9
// 198.866 us; speedup vs baseline: 1.4900x; 1.0362x over previous
//
#include <hip/hip_runtime.h>
#include <hip/hip_bf16.h>

typedef __attribute__((ext_vector_type(8))) short short8;
typedef __attribute__((ext_vector_type(4))) float f32x4;

static inline int cdiv(int a, int b) { return (a + b - 1) / b; }

__device__ inline float bf2f(unsigned short u) {
    union { unsigned int u; float f; } a; a.u = ((unsigned int)u) << 16; return a.f;
}
__device__ inline unsigned short f2bf(float f) {
    union { float f; unsigned int u; } a; a.f = f;
    unsigned int r = a.u + 0x7fff + ((a.u >> 16) & 1);
    return (unsigned short)(r >> 16);
}
__device__ inline void gload_lds16(const void* g, void* l) {
    __builtin_amdgcn_global_load_lds(
        (const __attribute__((address_space(1))) unsigned int*)g,
        (__attribute__((address_space(3))) unsigned int*)l, 16, 0, 0);
}

// ---------------- preprocessing ----------------
__global__ __launch_bounds__(256) void count_both_k(
    const int* __restrict__ rows, const int* __restrict__ cols,
    float* deg, int* indeg, int E)
{
    int e = blockIdx.x * 256 + threadIdx.x;
    if (e < E) {
        atomicAdd(&deg[rows[e]], 1.0f);
        atomicAdd(&indeg[cols[e]], 1);
    }
}

__global__ __launch_bounds__(256) void scan_block_k(
    const int* __restrict__ indeg, int* __restrict__ rowstart, int* __restrict__ bsums, int N)
{
    __shared__ int smem[256];
    int b = blockIdx.x, t = threadIdx.x;
    int base = b * 1024 + t * 4;
    int v0 = (base + 0 < N) ? indeg[base + 0] : 0;
    int v1 = (base + 1 < N) ? indeg[base + 1] : 0;
    int v2 = (base + 2 < N) ? indeg[base + 2] : 0;
    int v3 = (base + 3 < N) ? indeg[base + 3] : 0;
    int s = v0 + v1 + v2 + v3;
    smem[t] = s;
    __syncthreads();
    for (int off = 1; off < 256; off <<= 1) {
        int x = smem[t];
        int y = (t >= off) ? smem[t - off] : 0;
        __syncthreads();
        smem[t] = x + y;
        __syncthreads();
    }
    int excl = smem[t] - s;
    if (base + 0 < N) rowstart[base + 0] = excl;
    if (base + 1 < N) rowstart[base + 1] = excl + v0;
    if (base + 2 < N) rowstart[base + 2] = excl + v0 + v1;
    if (base + 3 < N) rowstart[base + 3] = excl + v0 + v1 + v2;
    if (t == 255) bsums[b] = smem[255];
}

// adds block offsets (re-scanning the <=64 block sums locally), inits cursor,
// finishes dinv = rsqrt(outdeg+1), writes rowstart[N]=E.  (scan_sums merged in)
__global__ __launch_bounds__(256) void scan_add_dinv_k(
    int* rowstart, int* cursor, const int* __restrict__ bsums, int nb,
    float* deg, int N, int E)
{
    __shared__ int sb[64];
    int t = threadIdx.x;
    int v = 0;
    if (t < 64) {
        v = (t < nb) ? bsums[t] : 0;
        sb[t] = v;
    }
    __syncthreads();
    for (int off = 1; off < 64; off <<= 1) {
        int x = 0, y = 0;
        if (t < 64) { x = sb[t]; y = (t >= off) ? sb[t - off] : 0; }
        __syncthreads();
        if (t < 64) sb[t] = x + y;
        __syncthreads();
    }
    if (t < 64) sb[t] -= v;   // exclusive
    __syncthreads();

    int i = blockIdx.x * 256 + t;
    if (i < N) {
        int r = rowstart[i] + sb[i >> 10];
        rowstart[i] = r;
        cursor[i] = r;
        deg[i] = rsqrtf(deg[i] + 1.0f);
    }
    if (blockIdx.x == 0 && t == 0) rowstart[N] = E;
}

__global__ __launch_bounds__(256) void fill_csr_k(
    const int* __restrict__ rows, const int* __restrict__ cols,
    int* cursor, int* __restrict__ csr, int E)
{
    int e = blockIdx.x * 256 + threadIdx.x;
    if (e < E) {
        int pos = atomicAdd(&cursor[cols[e]], 1);
        csr[pos] = rows[e];
    }
}

// weight transposes (to bf16 Wt[m][k]) + zero of deg/indeg counters, one launch
__global__ __launch_bounds__(256) void prep_weights_zero_k(
    const float* __restrict__ W1, const float* __restrict__ W2, const float* __restrict__ Wh,
    unsigned short* __restrict__ Wt1, unsigned short* __restrict__ Wt2, unsigned short* __restrict__ Wht,
    float4* __restrict__ zp, int nz4)
{
    int idx = blockIdx.x * 256 + threadIdx.x;
    if (idx < nz4) zp[idx] = make_float4(0.f, 0.f, 0.f, 0.f);
    if (idx < 65536) {
        int k = idx >> 8, m = idx & 255;
        Wt1[m * 256 + k] = f2bf(W1[idx]);
    } else if (idx < 131072) {
        int i = idx - 65536;
        int k = i >> 8, m = i & 255;
        Wt2[m * 256 + k] = f2bf(W2[i]);
    } else if (idx < 147456) {
        int i = idx - 131072;
        int k = i >> 6, m = i & 63;    // Wh is 256 x 64
        Wht[m * 256 + k] = f2bf(Wh[i]);
    }
}

// ---------------- MFMA GEMM, 2-phase double-buffered ----------------
// ASRC 0: A bf16 via global_load_lds; ASRC 1: A fp32 via reg-stage + cvt (T14).
// NYB 2: XCD-paired decode so both col-halves of an M-tile land on the same XCD
//        (dispatch id -> XCD is id%8; pair ids are congruent mod 8 -> A L2 reuse).
template<int BN, int MODE, int ASRC, int NYB>
__global__ __launch_bounds__(256) void gemm_mfma_k(
    const void* __restrict__ Asrc, const unsigned short* __restrict__ Wt,
    const float* __restrict__ bias, const float* __restrict__ rowscale,
    void* __restrict__ Cout, int N, int K, int Ncols)
{
    constexpr int NF = BN / 32;
    __shared__ __align__(16) unsigned short As[2][128 * 64];
    __shared__ __align__(16) unsigned short Bs[2][BN * 64];

    const unsigned short* Ab = (const unsigned short*)Asrc;
    const float* Af = (const float*)Asrc;

    int bx, by;
    if constexpr (NYB == 2) {
        const int nXB = (N + 127) >> 7;
        int d = blockIdx.x;
        int xcd = d & 7, slot = d >> 3;
        by = slot & 1;
        bx = xcd + 8 * (slot >> 1);
        if (bx >= nXB) return;
    } else {
        bx = blockIdx.x; by = 0;
    }

    const int tid = threadIdx.x;
    const int wid = tid >> 6;
    const int lane = tid & 63;
    const int wr = wid >> 1;
    const int wc = wid & 1;
    const int rowBase = bx * 128;
    const int colBase = by * BN;

    f32x4 acc[4][NF];
    #pragma unroll
    for (int m = 0; m < 4; ++m)
        #pragma unroll
        for (int n = 0; n < NF; ++n)
            acc[m][n] = (f32x4)0.0f;

    const int sslot = (lane & 7) ^ (lane >> 3);   // pre-swizzled source slot (m173)

    float4 areg[4][2];   // ASRC==1 staging regs (static-indexed, unrolled)

    auto stageA_g = [&](int buf, int k0) {
        #pragma unroll
        for (int it = 0; it < 4; ++it) {
            int ch = wid * 4 + it;
            int r = ch * 8 + (lane >> 3);
            int grow = rowBase + r; if (grow >= N) grow = N - 1;
            gload_lds16(Ab + (size_t)grow * K + k0 + sslot * 8, (void*)&As[buf][ch * 512]);
        }
    };
    auto issueA = [&](int k0) {
        #pragma unroll
        for (int it = 0; it < 4; ++it) {
            int ch = wid * 4 + it;
            int r = ch * 8 + (lane >> 3);
            int grow = rowBase + r; if (grow >= N) grow = N - 1;
            const float* src = Af + (size_t)grow * K + k0 + sslot * 8;
            areg[it][0] = *(const float4*)src;
            areg[it][1] = *(const float4*)(src + 4);
        }
    };
    auto writeA = [&](int buf) {
        #pragma unroll
        for (int it = 0; it < 4; ++it) {
            int ch = wid * 4 + it;
            short8 w;
            w[0] = (short)f2bf(areg[it][0].x); w[1] = (short)f2bf(areg[it][0].y);
            w[2] = (short)f2bf(areg[it][0].z); w[3] = (short)f2bf(areg[it][0].w);
            w[4] = (short)f2bf(areg[it][1].x); w[5] = (short)f2bf(areg[it][1].y);
            w[6] = (short)f2bf(areg[it][1].z); w[7] = (short)f2bf(areg[it][1].w);
            *(short8*)&As[buf][ch * 512 + lane * 8] = w;
        }
    };
    auto stageB = [&](int buf, int k0) {
        #pragma unroll
        for (int it = 0; it < NF; ++it) {
            int ch = wid * NF + it;
            int c = ch * 8 + (lane >> 3);
            gload_lds16(Wt + (size_t)(colBase + c) * K + k0 + sslot * 8, (void*)&Bs[buf][ch * 512]);
        }
    };

    const int nt = K >> 6;       // 4 for K=256
    if constexpr (ASRC == 0) {
        stageA_g(0, 0);
        stageB(0, 0);
    } else {
        issueA(0);
        stageB(0, 0);
        writeA(0);
    }
    __syncthreads();

    int cur = 0;
    for (int t = 0; t < nt; ++t) {
        if (t + 1 < nt) {
            if constexpr (ASRC == 0) stageA_g(cur ^ 1, (t + 1) * 64);
            else issueA((t + 1) * 64);
            stageB(cur ^ 1, (t + 1) * 64);
        }
        #pragma unroll
        for (int ks = 0; ks < 2; ++ks) {
            short8 af[4];
            #pragma unroll
            for (int m = 0; m < 4; ++m) {
                int R = wr * 64 + m * 16 + (lane & 15);
                int p = (ks * 4 + (lane >> 4)) ^ (R & 7);
                af[m] = *(const short8*)(&As[cur][R * 64 + p * 8]);
            }
            #pragma unroll
            for (int n = 0; n < NF; ++n) {
                int Cc = wc * (BN / 2) + n * 16 + (lane & 15);
                int p = (ks * 4 + (lane >> 4)) ^ (Cc & 7);
                short8 bf = *(const short8*)(&Bs[cur][Cc * 64 + p * 8]);
                #pragma unroll
                for (int m = 0; m < 4; ++m)
                    acc[m][n] = __builtin_amdgcn_mfma_f32_16x16x32_bf16(af[m], bf, acc[m][n], 0, 0, 0);
            }
        }
        if (t + 1 < nt) {
            if constexpr (ASRC == 1) writeA(cur ^ 1);  // HBM latency hidden under MFMA
            __syncthreads();
        }
        cur ^= 1;
    }

    // epilogue: C/D layout col=lane&15, row=(lane>>4)*4+q  [m89-verified]
    float bv[NF];
    int colv[NF];
    #pragma unroll
    for (int n = 0; n < NF; ++n) {
        colv[n] = colBase + wc * (BN / 2) + n * 16 + (lane & 15);
        bv[n] = bias[colv[n]];
    }
    #pragma unroll
    for (int m = 0; m < 4; ++m) {
        #pragma unroll
        for (int q = 0; q < 4; ++q) {
            int row = rowBase + wr * 64 + m * 16 + (lane >> 4) * 4 + q;
            if (row >= N) continue;
            if (MODE == 0) {
                float sc = rowscale[row];
                unsigned short* Cb = (unsigned short*)Cout;
                #pragma unroll
                for (int n = 0; n < NF; ++n)
                    Cb[(size_t)row * Ncols + colv[n]] = f2bf((acc[m][n][q] + bv[n]) * sc);
            } else {
                float* Cf = (float*)Cout;
                #pragma unroll
                for (int n = 0; n < NF; ++n)
                    Cf[(size_t)row * Ncols + colv[n]] = acc[m][n][q] + bv[n];
            }
        }
    }
}

// ---------------- gather aggregate (full 512B rows, 8-deep ILP) ----------------
__global__ __launch_bounds__(256) void gather_agg_k(
    const int* __restrict__ rowstart, const int* __restrict__ csr,
    const float* __restrict__ dinv, const unsigned short* __restrict__ hp,
    unsigned short* __restrict__ out, int N)
{
    int c = __builtin_amdgcn_readfirstlane(blockIdx.x * 4 + (threadIdx.x >> 6));
    if (c >= N) return;
    int lane = threadIdx.x & 63;
    const ushort4* base = (const ushort4*)hp;
    int beg = rowstart[c], end = rowstart[c + 1];

    ushort4 sv = base[(size_t)c * 64 + lane];    // self loop
    float a0 = bf2f(sv.x), a1 = bf2f(sv.y), a2 = bf2f(sv.z), a3 = bf2f(sv.w);

    int e = beg;
    for (; e + 8 <= end; e += 8) {
        ushort4 v0 = base[(size_t)csr[e + 0] * 64 + lane];
        ushort4 v1 = base[(size_t)csr[e + 1] * 64 + lane];
        ushort4 v2 = base[(size_t)csr[e + 2] * 64 + lane];
        ushort4 v3 = base[(size_t)csr[e + 3] * 64 + lane];
        ushort4 v4 = base[(size_t)csr[e + 4] * 64 + lane];
        ushort4 v5 = base[(size_t)csr[e + 5] * 64 + lane];
        ushort4 v6 = base[(size_t)csr[e + 6] * 64 + lane];
        ushort4 v7 = base[(size_t)csr[e + 7] * 64 + lane];
        a0 += bf2f(v0.x) + bf2f(v1.x) + bf2f(v2.x) + bf2f(v3.x)
            + bf2f(v4.x) + bf2f(v5.x) + bf2f(v6.x) + bf2f(v7.x);
        a1 += bf2f(v0.y) + bf2f(v1.y) + bf2f(v2.y) + bf2f(v3.y)
            + bf2f(v4.y) + bf2f(v5.y) + bf2f(v6.y) + bf2f(v7.y);
        a2 += bf2f(v0.z) + bf2f(v1.z) + bf2f(v2.z) + bf2f(v3.z)
            + bf2f(v4.z) + bf2f(v5.z) + bf2f(v6.z) + bf2f(v7.z);
        a3 += bf2f(v0.w) + bf2f(v1.w) + bf2f(v2.w) + bf2f(v3.w)
            + bf2f(v4.w) + bf2f(v5.w) + bf2f(v6.w) + bf2f(v7.w);
    }
    for (; e + 4 <= end; e += 4) {
        ushort4 v0 = base[(size_t)csr[e + 0] * 64 + lane];
        ushort4 v1 = base[(size_t)csr[e + 1] * 64 + lane];
        ushort4 v2 = base[(size_t)csr[e + 2] * 64 + lane];
        ushort4 v3 = base[(size_t)csr[e + 3] * 64 + lane];
        a0 += bf2f(v0.x) + bf2f(v1.x) + bf2f(v2.x) + bf2f(v3.x);
        a1 += bf2f(v0.y) + bf2f(v1.y) + bf2f(v2.y) + bf2f(v3.y);
        a2 += bf2f(v0.z) + bf2f(v1.z) + bf2f(v2.z) + bf2f(v3.z);
        a3 += bf2f(v0.w) + bf2f(v1.w) + bf2f(v2.w) + bf2f(v3.w);
    }
    for (; e < end; ++e) {
        ushort4 v0 = base[(size_t)csr[e] * 64 + lane];
        a0 += bf2f(v0.x); a1 += bf2f(v0.y); a2 += bf2f(v0.z); a3 += bf2f(v0.w);
    }

    float sc = dinv[c];
    ushort4 o;
    o.x = f2bf(fmaxf(sc * a0, 0.f));
    o.y = f2bf(fmaxf(sc * a1, 0.f));
    o.z = f2bf(fmaxf(sc * a2, 0.f));
    o.w = f2bf(fmaxf(sc * a3, 0.f));
    ((ushort4*)out)[(size_t)c * 64 + lane] = o;
}

extern "C" void kernel_launch(void* const* d_in, const int* in_sizes, int n_in,
                              void* d_out, int out_size, void* d_ws, size_t ws_size,
                              hipStream_t stream) {
    const float* x  = (const float*)d_in[0];
    const int*  ei  = (const int*)d_in[1];
    const float* W1 = (const float*)d_in[2];
    const float* b1 = (const float*)d_in[3];
    const float* W2 = (const float*)d_in[4];
    const float* b2 = (const float*)d_in[5];
    const float* Wh = (const float*)d_in[6];
    const float* bh = (const float*)d_in[7];
    float* out = (float*)d_out;

    const int N = in_sizes[0] / 256;       // 50000
    const int E = in_sizes[1] / 2;         // 400000
    const int H = 256;
    const int C = 64;
    const int* rows = ei;
    const int* cols = ei + E;

    char* ws = (char*)d_ws;
    size_t off = 0;
    auto alloc = [&](size_t bytes) {
        void* p = ws + off;
        off = (off + bytes + 255) & ~(size_t)255;
        return p;
    };
    float* deg      = (float*)alloc((size_t)2 * N * 4);  // deg (float) + indeg (int)
    int*   indeg    = (int*)(deg + N);                   // reused as cursor
    int*   rowstart = (int*)alloc((size_t)(N + 1) * 4);
    int*   bsums    = (int*)alloc(256 * 4);
    int*   csr      = (int*)alloc((size_t)E * 4);
    unsigned short* bufH = (unsigned short*)alloc((size_t)N * H * 2);
    unsigned short* bufA = (unsigned short*)alloc((size_t)N * H * 2);
    unsigned short* Wt1  = (unsigned short*)alloc((size_t)H * H * 2);
    unsigned short* Wt2  = (unsigned short*)alloc((size_t)H * H * 2);
    unsigned short* Wht  = (unsigned short*)alloc((size_t)C * H * 2);

    const int nb = cdiv(N, 1024);          // 49

    // ---- weights + counter-zero, then degrees + CSR ----
    prep_weights_zero_k<<<cdiv(147456, 256), 256, 0, stream>>>(
        W1, W2, Wh, Wt1, Wt2, Wht, (float4*)deg, 2 * N / 4);
    count_both_k<<<cdiv(E, 256), 256, 0, stream>>>(rows, cols, deg, indeg, E);
    scan_block_k<<<nb, 256, 0, stream>>>(indeg, rowstart, bsums, N);
    scan_add_dinv_k<<<cdiv(N, 256), 256, 0, stream>>>(rowstart, indeg, bsums, nb, deg, N, E);
    fill_csr_k<<<cdiv(E, 256), 256, 0, stream>>>(rows, cols, indeg, csr, E);
    float* dinv = deg;

    const int nXB = cdiv(N, 128);          // 391
    dim3 g1(16 * cdiv(nXB, 8));            // 784, XCD-paired decode in-kernel
    dim3 gh(nXB);

    // ---- layer 1 (fp32 x read directly; conversion fused into staging) ----
    gemm_mfma_k<128, 0, 1, 2><<<g1, 256, 0, stream>>>(x, Wt1, b1, dinv, bufH, N, H, H);
    gather_agg_k<<<cdiv(N, 4), 256, 0, stream>>>(rowstart, csr, dinv, bufH, bufA, N);

    // ---- layer 2 ----
    gemm_mfma_k<128, 0, 0, 2><<<g1, 256, 0, stream>>>(bufA, Wt2, b2, dinv, bufH, N, H, H);
    gather_agg_k<<<cdiv(N, 4), 256, 0, stream>>>(rowstart, csr, dinv, bufH, bufA, N);

    // ---- head ----
    gemm_mfma_k<64, 1, 0, 1><<<gh, 256, 0, stream>>>(bufA, Wht, bh, nullptr, out, N, H, C);
}